// Round 7
// baseline (409.948 us; speedup 1.0000x reference)
//
#include <hip/hip_runtime.h>
#include <hip/hip_cooperative_groups.h>
#include <hip/hip_bf16.h>
#include <math.h>

namespace cg = cooperative_groups;

#define BB 64
#define NN 128
#define DD 32
#define PP (NN * (NN - 1))   // 16256
#define EPSF 1e-5f
#define NBLK 512

typedef __attribute__((ext_vector_type(8))) short bf16x8;
typedef __attribute__((ext_vector_type(4))) float f32x4;

static __device__ __forceinline__ unsigned short f2bf(float x) {
    unsigned u = __builtin_bit_cast(unsigned, x);
    u += 0x7fff + ((u >> 16) & 1);          // RNE
    return (unsigned short)(u >> 16);
}
static __device__ __forceinline__ float leakyf(float x) {
    return fmaxf(x, 0.01f * x);
}

struct Params {
    const float *inputs, *W1, *b1, *g1, *be1, *W2, *b2, *W3, *b3;
    const float *Wf1, *bf1, *gf, *bef, *Wf2, *bf2;
    float *AT, *BT;
    unsigned short *ATh, *BTh;
    float *SQp;                 // [128 nodes][8 oct] float4 {sa,qa,sb,qb}
    float *statA, *statB, *agg, *f, *fpartA, *fpartB;
    unsigned short *W2p, *W3p;
    float *edges_out, *outp;
};

// phase = -1: cooperative, all phases with grid.sync().
// phase = 0..3: run one phase (regular launch fallback).
__global__ __launch_bounds__(256, 2) void fused_kernel(Params P, int phase)
{
    cg::grid_group grid = cg::this_grid();
    const bool all = (phase < 0);
    __shared__ __align__(16) char smem[17472];
    int tid = threadIdx.x;
    int bx = blockIdx.x;
    int lane = tid & 63;
    int w = tid >> 6;

    // ================= Phase 1: proj + partial sums + pack + zero ==========
    if (all || phase == 0) {
        float* Xs  = (float*)smem;            // [8][33] = 264
        float* W1s = Xs + 264;                // [64][32] flat k*32+j
        float* red = W1s + 2048;              // [16]

        for (int idx = tid; idx < 2048; idx += 256) W1s[idx] = P.W1[idx];

        int j = tid & 31, rb = tid >> 5;
        float b1j = P.b1[j];

        for (int unit = bx; unit < 1024; unit += NBLK) {
            int n = unit >> 3, o = unit & 7;
            int b = o * 8 + rb;
            __syncthreads();   // W1s ready / prior-unit Xs,red consumers done
            Xs[rb * 33 + j] = P.inputs[((size_t)b << 12) + ((size_t)n << 5) + j];
            __syncthreads();

            float a = b1j, c = 0.f;
            #pragma unroll
            for (int k = 0; k < 32; ++k) {
                float x = Xs[rb * 33 + k];
                a += x * W1s[k * 32 + j];
                c += x * W1s[(32 + k) * 32 + j];
            }
            size_t off = ((size_t)n * 64 + b) * 32 + j;
            P.AT[off] = a;  P.BT[off] = c;
            P.ATh[off] = f2bf(a);  P.BTh[off] = f2bf(c);

            float sa = a, qa = a * a, sb = c, qb = c * c;
            #pragma unroll
            for (int d = 32; d > 0; d >>= 1) {
                sa += __shfl_down(sa, d, 64);
                qa += __shfl_down(qa, d, 64);
                sb += __shfl_down(sb, d, 64);
                qb += __shfl_down(qb, d, 64);
            }
            if (lane == 0) { red[w*4+0] = sa; red[w*4+1] = qa; red[w*4+2] = sb; red[w*4+3] = qb; }
            __syncthreads();
            if (tid == 0) {
                float4 v;
                v.x = red[0] + red[4] + red[8]  + red[12];
                v.y = red[1] + red[5] + red[9]  + red[13];
                v.z = red[2] + red[6] + red[10] + red[14];
                v.w = red[3] + red[7] + red[11] + red[15];
                ((float4*)P.SQp)[n * 8 + o] = v;
            }
        }

        if (bx == 0 && tid < 64) {      // pack W2/W3 into bf16 B-frag layout
            int l = tid, nn2 = l & 15, kc = l >> 4;
            #pragma unroll
            for (int ct = 0; ct < 2; ++ct)
                #pragma unroll
                for (int jj = 0; jj < 8; ++jj) {
                    int k = kc * 8 + jj;
                    P.W2p[(ct * 64 + l) * 8 + jj] = f2bf(P.W2[k * 32 + ct * 16 + nn2]);
                }
            #pragma unroll
            for (int ct = 0; ct < 3; ++ct)
                #pragma unroll
                for (int jj = 0; jj < 8; ++jj) {
                    int k = kc * 8 + jj;
                    int c2 = ct * 16 + nn2;
                    P.W3p[(ct * 64 + l) * 8 + jj] = f2bf(c2 < 33 ? P.W3[k * 33 + c2] : 0.f);
                }
        }
        if (bx == 1) {
            for (int idx = tid; idx < 1024; idx += 256) {
                P.fpartA[idx] = 0.f;
                P.fpartB[idx] = 0.f;
            }
        }
    }
    if (all) grid.sync();

    // ================= Phase 2: LN stats via bf16 MFMA cross-GEMM ==========
    if (all || phase == 1) {
        float* part = (float*)smem;           // [4][64][4]
        if (bx < 64) {
            int s0 = (bx >> 3) * 16, t0 = (bx & 7) * 16;
            int m = lane & 15, kc = lane >> 4;
            const unsigned short* abase = P.ATh + (size_t)(s0 + m) * 2048 + kc * 8 + w * 512;
            const unsigned short* bbase = P.BTh + (size_t)(t0 + m) * 2048 + kc * 8 + w * 512;

            f32x4 acc = {0.f, 0.f, 0.f, 0.f};
            #pragma unroll
            for (int step = 0; step < 16; ++step) {
                bf16x8 av = *(const bf16x8*)(abase + step * 32);
                bf16x8 bv = *(const bf16x8*)(bbase + step * 32);
                acc = __builtin_amdgcn_mfma_f32_16x16x32_bf16(av, bv, acc, 0, 0, 0);
            }
            *(f32x4*)&part[(w * 64 + lane) * 4] = acc;
            __syncthreads();

            if (w == 0) {
                #pragma unroll
                for (int ww = 1; ww < 4; ++ww) {
                    f32x4 o2 = *(const f32x4*)&part[(ww * 64 + lane) * 4];
                    acc[0] += o2[0]; acc[1] += o2[1]; acc[2] += o2[2]; acc[3] += o2[3];
                }
                int col = lane & 15, quad = lane >> 4;
                int t = t0 + col;
                float sbt = 0.f, qbt = 0.f;
                #pragma unroll
                for (int o2 = 0; o2 < 8; ++o2) {
                    float4 v = ((const float4*)P.SQp)[t * 8 + o2];
                    sbt += v.z; qbt += v.w;
                }
                #pragma unroll
                for (int r = 0; r < 4; ++r) {
                    int s = s0 + quad * 4 + r;
                    if (s != t) {
                        float sas = 0.f, qas = 0.f;
                        #pragma unroll
                        for (int o2 = 0; o2 < 8; ++o2) {
                            float4 v = ((const float4*)P.SQp)[s * 8 + o2];
                            sas += v.x; qas += v.y;
                        }
                        int e = t - (t > s);
                        int p = s * 127 + e;
                        float S = sas + sbt;
                        float Q = qas + qbt + 2.f * acc[r];
                        float mean = S * (1.f / 2048.f);
                        float var  = Q * (1.f / 2048.f) - mean * mean;
                        float inv  = rsqrtf(var + EPSF);
                        float sc   = inv * P.g1[p];
                        P.statA[p] = sc;
                        P.statB[p] = P.be1[p] - mean * sc;
                    }
                }
            }
        }
    }
    if (all) grid.sync();

    // ================= Phase 3: MFMA edge MLP + agg + f-row =================
    if (all || phase == 2) {
        unsigned short* Abuf = (unsigned short*)smem;          // [8][64][8]
        unsigned short* Hbuf = Abuf + 4096;                    // [8][64][8]
        float* evb    = (float*)(smem + 16384);                // [128]
        float* aggbuf = evb + 128;                             // [32]

        int s = bx & 127;        // same s for unit bx and bx+512

        int e2 = tid >> 1;
        int half = tid & 1;
        int k0 = half * 16;
        int m = e2 & 15, r = e2 >> 4;
        int L0 = 2 * half * 16 + m;
        bool valid = (e2 < 127);
        int t = valid ? (e2 + (e2 >= s)) : 0;
        int pe = s * 127 + (valid ? e2 : 126);
        float sc = 0.f, sh = 0.f;
        if (valid) { sc = P.statA[pe]; sh = P.statB[pe]; }

        int col = lane & 15, q4 = (lane >> 4) * 4;
        bf16x8 wb2[2], wb3[3];
        wb2[0] = *(const bf16x8*)(P.W2p + (0 * 64 + lane) * 8);
        wb2[1] = *(const bf16x8*)(P.W2p + (1 * 64 + lane) * 8);
        wb3[0] = *(const bf16x8*)(P.W3p + (0 * 64 + lane) * 8);
        wb3[1] = *(const bf16x8*)(P.W3p + (1 * 64 + lane) * 8);
        wb3[2] = *(const bf16x8*)(P.W3p + (2 * 64 + lane) * 8);
        float b2c0 = P.b2[col], b2c1 = P.b2[16 + col];
        float b3c[3];
        #pragma unroll
        for (int ct = 0; ct < 3; ++ct) {
            int c = ct * 16 + col;
            b3c[ct] = (c < 33) ? P.b3[c] : 0.f;
        }

        for (int u = 0; u < 2; ++u) {
            int o = (bx >> 7) + u * 4;      // unit = bx + u*512
            for (int bi = 0; bi < 8; ++bi) {
                int b = o * 8 + bi;
                __syncthreads();        // guard prior-iter LDS consumers
                if (tid < 32) aggbuf[tid] = 0.f;

                float nh[16];
                if (valid) {
                    const float4* brow = (const float4*)(P.BT + ((size_t)t * 64 + b) * 32 + k0);
                    const float4* ar4  = (const float4*)(P.AT + ((size_t)s * 64 + b) * 32 + k0);
                    #pragma unroll
                    for (int q = 0; q < 4; ++q) {
                        float4 bv = brow[q];
                        float4 av = ar4[q];
                        nh[4*q+0] = leakyf((av.x + bv.x) * sc + sh);
                        nh[4*q+1] = leakyf((av.y + bv.y) * sc + sh);
                        nh[4*q+2] = leakyf((av.z + bv.z) * sc + sh);
                        nh[4*q+3] = leakyf((av.w + bv.w) * sc + sh);
                    }
                } else {
                    #pragma unroll
                    for (int q = 0; q < 16; ++q) nh[q] = 0.f;
                }
                bf16x8 v0, v1;
                #pragma unroll
                for (int jj = 0; jj < 8; ++jj) {
                    v0[jj] = (short)f2bf(nh[jj]);
                    v1[jj] = (short)f2bf(nh[8 + jj]);
                }
                *(bf16x8*)&Abuf[((size_t)r * 64 + L0) * 8]        = v0;
                *(bf16x8*)&Abuf[((size_t)r * 64 + L0 + 16) * 8]   = v1;
                __syncthreads();

                // GEMM2
                #pragma unroll
                for (int rt = 0; rt < 2; ++rt) {
                    int r2 = w * 2 + rt;
                    bf16x8 a = *(const bf16x8*)&Abuf[((size_t)r2 * 64 + lane) * 8];
                    f32x4 c0 = {0.f, 0.f, 0.f, 0.f}, c1 = {0.f, 0.f, 0.f, 0.f};
                    c0 = __builtin_amdgcn_mfma_f32_16x16x32_bf16(a, wb2[0], c0, 0, 0, 0);
                    c1 = __builtin_amdgcn_mfma_f32_16x16x32_bf16(a, wb2[1], c1, 0, 0, 0);
                    #pragma unroll
                    for (int reg = 0; reg < 4; ++reg) {
                        float x = leakyf(c0[reg] + b2c0);
                        int c = col;
                        Hbuf[((size_t)r2 * 64 + (c >> 3) * 16 + q4 + reg) * 8 + (c & 7)] = f2bf(x);
                        float y = leakyf(c1[reg] + b2c1);
                        int c2 = 16 + col;
                        Hbuf[((size_t)r2 * 64 + (c2 >> 3) * 16 + q4 + reg) * 8 + (c2 & 7)] = f2bf(y);
                    }
                }
                __syncthreads();

                // GEMM3
                f32x4 oo[2][3];
                #pragma unroll
                for (int rt = 0; rt < 2; ++rt) {
                    int r2 = w * 2 + rt;
                    bf16x8 a2 = *(const bf16x8*)&Hbuf[((size_t)r2 * 64 + lane) * 8];
                    #pragma unroll
                    for (int ct = 0; ct < 3; ++ct) {
                        f32x4 cc = {0.f, 0.f, 0.f, 0.f};
                        oo[rt][ct] = __builtin_amdgcn_mfma_f32_16x16x32_bf16(a2, wb3[ct], cc, 0, 0, 0);
                    }
                }

                if (col == 0) {
                    #pragma unroll
                    for (int rt = 0; rt < 2; ++rt) {
                        int row0 = (w * 2 + rt) * 16 + q4;
                        float e0 = 1.f / (1.f + __expf(-(oo[rt][0][0] + b3c[0])));
                        float e1 = 1.f / (1.f + __expf(-(oo[rt][0][1] + b3c[0])));
                        float e2v = 1.f / (1.f + __expf(-(oo[rt][0][2] + b3c[0])));
                        float e3 = 1.f / (1.f + __expf(-(oo[rt][0][3] + b3c[0])));
                        float4 ev4;
                        ev4.x = e0; ev4.y = e1; ev4.z = e2v;
                        ev4.w = (row0 == 124) ? 0.f : e3;
                        *(float4*)&evb[row0] = ev4;
                        float* ep = P.edges_out + (size_t)b * PP + s * 127 + row0;
                        ep[0] = e0; ep[1] = e1; ep[2] = e2v;
                        if (row0 != 124) ep[3] = e3;
                    }
                }
                __syncthreads();

                #pragma unroll
                for (int ct = 0; ct < 3; ++ct) {
                    int c = ct * 16 + col;
                    if (c >= 1 && c <= 32) {
                        float part = 0.f;
                        #pragma unroll
                        for (int rt = 0; rt < 2; ++rt) {
                            int row0 = (w * 2 + rt) * 16 + q4;
                            float4 ev4 = *(const float4*)&evb[row0];
                            float bb3 = b3c[ct];
                            part += ev4.x * (oo[rt][ct][0] + bb3);
                            part += ev4.y * (oo[rt][ct][1] + bb3);
                            part += ev4.z * (oo[rt][ct][2] + bb3);
                            part += ev4.w * (oo[rt][ct][3] + bb3);
                        }
                        atomicAdd(&aggbuf[c - 1], part);
                    }
                }
                __syncthreads();

                size_t row = (size_t)b * 128 + s;
                if (tid < 32) P.agg[row * 32 + tid] = aggbuf[tid];
                if (tid < 16) {
                    const float* xrow = P.inputs + row * 32;
                    float acc = P.bf1[tid];
                    #pragma unroll
                    for (int k = 0; k < 32; ++k) acc += xrow[k] * P.Wf1[k * 16 + tid];
                    #pragma unroll
                    for (int k = 0; k < 32; ++k) acc += aggbuf[k] * P.Wf1[(32 + k) * 16 + tid];
                    P.f[row * 16 + tid] = acc;
                    int bucket = ((bx << 3) + bi) & 63;
                    atomicAdd(&P.fpartA[bucket * 16 + tid], acc);
                    atomicAdd(&P.fpartB[bucket * 16 + tid], acc * acc);
                }
            }
        }
    }
    if (all) grid.sync();

    // ================= Phase 4: f-stats reduce + out =======================
    if (all || phase == 3) {
        float* Wf2s = (float*)smem;           // [16][32]
        float* sc   = Wf2s + 512;             // [16]
        float* sh   = sc + 16;                // [16]
        float* fs   = sh + 16;                // [8][16]

        for (int idx = tid; idx < 512; idx += 256) Wf2s[idx] = P.Wf2[idx];
        if (tid < 16) {
            float S = 0.f, Q = 0.f;
            #pragma unroll
            for (int g = 0; g < 64; ++g) {
                S += P.fpartA[g * 16 + tid];
                Q += P.fpartB[g * 16 + tid];
            }
            float mean = S * (1.f / 8192.f);
            float var  = Q * (1.f / 8192.f) - mean * mean;
            float inv  = rsqrtf(var + EPSF);
            float s2   = inv * P.gf[tid];
            sc[tid] = s2;
            sh[tid] = P.bef[tid] - mean * s2;
        }

        for (int u = 0; u < 2; ++u) {
            int unit = bx + u * NBLK;
            int row0 = unit * 8;
            __syncthreads();    // Wf2s/sc/sh visible; prior fs readers done
            if (tid < 128) {
                int r = tid >> 4, j = tid & 15;
                fs[r * 16 + j] = P.f[(size_t)(row0 + r) * 16 + j];
            }
            __syncthreads();

            int rl = tid >> 5, d = tid & 31;
            float acc = P.bf2[d];
            #pragma unroll
            for (int j = 0; j < 16; ++j) {
                float v = fs[rl * 16 + j] * sc[j] + sh[j];
                v = leakyf(v);
                acc += v * Wf2s[j * 32 + d];
            }
            P.outp[(size_t)(row0 + rl) * 32 + d] = acc;
        }
    }
}

extern "C" void kernel_launch(void* const* d_in, const int* in_sizes, int n_in,
                              void* d_out, int out_size, void* d_ws, size_t ws_size,
                              hipStream_t stream) {
    Params P;
    P.inputs = (const float*)d_in[0];
    P.W1  = (const float*)d_in[3];
    P.b1  = (const float*)d_in[4];
    P.g1  = (const float*)d_in[5];
    P.be1 = (const float*)d_in[6];
    P.W2  = (const float*)d_in[7];
    P.b2  = (const float*)d_in[8];
    P.W3  = (const float*)d_in[9];
    P.b3  = (const float*)d_in[10];
    P.Wf1 = (const float*)d_in[11];
    P.bf1 = (const float*)d_in[12];
    P.gf  = (const float*)d_in[13];
    P.bef = (const float*)d_in[14];
    P.Wf2 = (const float*)d_in[15];
    P.bf2 = (const float*)d_in[16];

    float* ws = (float*)d_ws;
    P.AT     = ws;                              // 262144
    P.BT     = ws + 262144;                     // 262144
    P.ATh    = (unsigned short*)(ws + 524288);  // 262144 ush (131072 f)
    P.BTh    = P.ATh + 262144;                  // 262144 ush (131072 f)
    P.SQp    = ws + 786432;                     // 4096
    P.statA  = ws + 790528;                     // 16256
    P.statB  = ws + 806784;                     // 16256
    P.agg    = ws + 823040;                     // 262144
    P.f      = ws + 1085184;                    // 131072
    P.fpartA = ws + 1216256;                    // 1024
    P.fpartB = ws + 1217280;                    // 1024
    P.W2p    = (unsigned short*)(ws + 1218304); // 1024 ush
    P.W3p    = P.W2p + 1024;                    // 1536 ush

    P.edges_out = (float*)d_out;                     // B*P
    P.outp      = P.edges_out + (size_t)BB * PP;     // B*N*D

    // Capture-safe path decision: pure host occupancy query (no stream ops).
    int maxBlocksPerCU = 0;
    hipError_t qerr = hipOccupancyMaxActiveBlocksPerMultiprocessor(
        &maxBlocksPerCU, (const void*)fused_kernel, 256, 0);
    bool coop_ok = (qerr == hipSuccess) && (maxBlocksPerCU >= 2);

    if (coop_ok) {
        int phase = -1;
        void* args[] = { &P, &phase };
        hipError_t lerr = hipLaunchCooperativeKernel(
            (void*)fused_kernel, dim3(NBLK), dim3(256), args, 0, stream);
        if (lerr == hipSuccess) return;
        (void)hipGetLastError();   // clear sticky error, fall through
    }
    for (int ph = 0; ph < 4; ++ph)
        fused_kernel<<<NBLK, 256, 0, stream>>>(P, ph);
}

// Round 9
// 145.300 us; speedup vs baseline: 2.8214x; 2.8214x over previous
//
#include <hip/hip_runtime.h>
#include <hip/hip_bf16.h>
#include <math.h>

#define BB 64
#define NN 128
#define DD 32
#define PP (NN * (NN - 1))   // 16256
#define EPSF 1e-5f

typedef __attribute__((ext_vector_type(8))) short bf16x8;
typedef __attribute__((ext_vector_type(4))) float f32x4;

static __device__ __forceinline__ unsigned short f2bf(float x) {
    unsigned u = __builtin_bit_cast(unsigned, x);
    u += 0x7fff + ((u >> 16) & 1);          // RNE
    return (unsigned short)(u >> 16);
}
static __device__ __forceinline__ float leakyf(float x) {
    return fmaxf(x, 0.01f * x);
}

// ============ Kernel 1: proj + per-node partial sums + pack + zero ============
// 512 blocks: n = bx>>2, b-quarter q = bx&3 (16 rows). 256 thr.
__global__ __launch_bounds__(256) void proj_kernel(
    const float* __restrict__ inputs, const float* __restrict__ W1,
    const float* __restrict__ b1,
    const float* __restrict__ W2, const float* __restrict__ W3,
    float* __restrict__ AT, float* __restrict__ BT,
    unsigned short* __restrict__ ATh, unsigned short* __restrict__ BTh,
    float* __restrict__ SQp,
    unsigned short* __restrict__ W2p, unsigned short* __restrict__ W3p,
    float* __restrict__ fpartA, float* __restrict__ fpartB)
{
    __shared__ float Xs[16 * 33];
    __shared__ float W1s[2048];
    __shared__ float red[16];

    int tid = threadIdx.x;
    int n = blockIdx.x >> 2, q = blockIdx.x & 3;

    for (int idx = tid; idx < 2048; idx += 256) W1s[idx] = W1[idx];
    for (int idx = tid; idx < 512; idx += 256) {
        int r = idx >> 5, d = idx & 31;
        Xs[r * 33 + d] = inputs[(size_t)(q * 16 + r) * 4096 + n * 32 + d];
    }
    __syncthreads();

    int j = tid & 31, rb = tid >> 5;
    int lane = tid & 63, w = tid >> 6;
    float b1j = b1[j];
    float sa = 0.f, qa = 0.f, sb = 0.f, qb = 0.f;
    #pragma unroll
    for (int i = 0; i < 2; ++i) {
        int r = rb * 2 + i;
        int b = q * 16 + r;
        float a = b1j, c = 0.f;
        #pragma unroll
        for (int k = 0; k < 32; ++k) {
            float x = Xs[r * 33 + k];
            a += x * W1s[k * 32 + j];
            c += x * W1s[(32 + k) * 32 + j];
        }
        size_t off = ((size_t)n * 64 + b) * 32 + j;
        AT[off] = a;  BT[off] = c;
        ATh[off] = f2bf(a);  BTh[off] = f2bf(c);
        sa += a; qa += a * a; sb += c; qb += c * c;
    }
    #pragma unroll
    for (int d = 32; d > 0; d >>= 1) {
        sa += __shfl_down(sa, d, 64);
        qa += __shfl_down(qa, d, 64);
        sb += __shfl_down(sb, d, 64);
        qb += __shfl_down(qb, d, 64);
    }
    if (lane == 0) { red[w*4+0] = sa; red[w*4+1] = qa; red[w*4+2] = sb; red[w*4+3] = qb; }
    __syncthreads();
    if (tid == 0) {
        float4 v;
        v.x = red[0] + red[4] + red[8]  + red[12];
        v.y = red[1] + red[5] + red[9]  + red[13];
        v.z = red[2] + red[6] + red[10] + red[14];
        v.w = red[3] + red[7] + red[11] + red[15];
        ((float4*)SQp)[n * 4 + q] = v;
    }

    if (blockIdx.x == 0 && tid < 64) {      // pack W2/W3 -> bf16 B-frag layout
        int l = tid, nn2 = l & 15, kc = l >> 4;
        #pragma unroll
        for (int ct = 0; ct < 2; ++ct)
            #pragma unroll
            for (int jj = 0; jj < 8; ++jj) {
                int k = kc * 8 + jj;
                W2p[(ct * 64 + l) * 8 + jj] = f2bf(W2[k * 32 + ct * 16 + nn2]);
            }
        #pragma unroll
        for (int ct = 0; ct < 3; ++ct)
            #pragma unroll
            for (int jj = 0; jj < 8; ++jj) {
                int k = kc * 8 + jj;
                int c2 = ct * 16 + nn2;
                W3p[(ct * 64 + l) * 8 + jj] = f2bf(c2 < 33 ? W3[k * 33 + c2] : 0.f);
            }
    }
    if (blockIdx.x == 1) {
        for (int idx = tid; idx < 1024; idx += 256) {
            fpartA[idx] = 0.f;
            fpartB[idx] = 0.f;
        }
    }
}

// ============ Kernel 2: LN stats via bf16 MFMA cross-GEMM ============
// 64 blocks: 16x16 (s,t) tile; 4 waves split K=2048; dual accumulators.
__global__ __launch_bounds__(256) void stats2_kernel(
    const unsigned short* __restrict__ ATh, const unsigned short* __restrict__ BTh,
    const float* __restrict__ SQp,
    const float* __restrict__ g1, const float* __restrict__ be1,
    float* __restrict__ statA, float* __restrict__ statB)
{
    __shared__ __align__(16) float part[4 * 64 * 4];
    int tid = threadIdx.x;
    int lane = tid & 63, w = tid >> 6;
    int s0 = (blockIdx.x >> 3) * 16, t0 = (blockIdx.x & 7) * 16;

    int m = lane & 15, kc = lane >> 4;
    const unsigned short* abase = ATh + (size_t)(s0 + m) * 2048 + kc * 8 + w * 512;
    const unsigned short* bbase = BTh + (size_t)(t0 + m) * 2048 + kc * 8 + w * 512;

    f32x4 acc0 = {0.f, 0.f, 0.f, 0.f}, acc1 = {0.f, 0.f, 0.f, 0.f};
    #pragma unroll
    for (int step = 0; step < 8; ++step) {
        bf16x8 av0 = *(const bf16x8*)(abase + (2 * step) * 32);
        bf16x8 bv0 = *(const bf16x8*)(bbase + (2 * step) * 32);
        acc0 = __builtin_amdgcn_mfma_f32_16x16x32_bf16(av0, bv0, acc0, 0, 0, 0);
        bf16x8 av1 = *(const bf16x8*)(abase + (2 * step + 1) * 32);
        bf16x8 bv1 = *(const bf16x8*)(bbase + (2 * step + 1) * 32);
        acc1 = __builtin_amdgcn_mfma_f32_16x16x32_bf16(av1, bv1, acc1, 0, 0, 0);
    }
    f32x4 acc;
    acc[0] = acc0[0] + acc1[0]; acc[1] = acc0[1] + acc1[1];
    acc[2] = acc0[2] + acc1[2]; acc[3] = acc0[3] + acc1[3];
    *(f32x4*)&part[(w * 64 + lane) * 4] = acc;
    __syncthreads();

    if (w == 0) {
        #pragma unroll
        for (int ww = 1; ww < 4; ++ww) {
            f32x4 o2 = *(const f32x4*)&part[(ww * 64 + lane) * 4];
            acc[0] += o2[0]; acc[1] += o2[1]; acc[2] += o2[2]; acc[3] += o2[3];
        }
        int col = lane & 15, quad = lane >> 4;
        int t = t0 + col;
        float sbt = 0.f, qbt = 0.f;
        #pragma unroll
        for (int o2 = 0; o2 < 4; ++o2) {
            float4 v = ((const float4*)SQp)[t * 4 + o2];
            sbt += v.z; qbt += v.w;
        }
        #pragma unroll
        for (int r = 0; r < 4; ++r) {
            int s = s0 + quad * 4 + r;
            if (s != t) {
                float sas = 0.f, qas = 0.f;
                #pragma unroll
                for (int o2 = 0; o2 < 4; ++o2) {
                    float4 v = ((const float4*)SQp)[s * 4 + o2];
                    sas += v.x; qas += v.y;
                }
                int e = t - (t > s);
                int p = s * 127 + e;
                float S = sas + sbt;
                float Q = qas + qbt + 2.f * acc[r];
                float mean = S * (1.f / 2048.f);
                float var  = Q * (1.f / 2048.f) - mean * mean;
                float inv  = rsqrtf(var + EPSF);
                float sc   = inv * g1[p];
                statA[p] = sc;
                statB[p] = be1[p] - mean * sc;
            }
        }
    }
}

// ============ Kernel 3: MFMA edge MLP + agg + f-row ============
// 2048 blocks: s = bx&127, o = bx>>7 (0..15), 4 b-iterations (b = o*4+bi).
__global__ __launch_bounds__(256) void edges_kernel(
    const float* __restrict__ AT, const float* __restrict__ BT,
    const float* __restrict__ statA, const float* __restrict__ statB,
    const unsigned short* __restrict__ W2p, const unsigned short* __restrict__ W3p,
    const float* __restrict__ b2, const float* __restrict__ b3,
    const float* __restrict__ inputs, const float* __restrict__ Wf1,
    const float* __restrict__ bf1,
    float* __restrict__ edges_out,
    float* __restrict__ f, float* __restrict__ fpartA, float* __restrict__ fpartB)
{
    __shared__ __align__(16) unsigned short Abuf[4096];   // [8 tiles][64][8]
    __shared__ __align__(16) unsigned short Hbuf[4096];
    __shared__ float Wf1s[1024];
    __shared__ float aggbuf[4][32];                       // per-wave slices

    int tid = threadIdx.x;
    int s = blockIdx.x & 127;
    int o = blockIdx.x >> 7;
    int lane = tid & 63, w = tid >> 6;

    for (int idx = tid; idx < 1024; idx += 256) Wf1s[idx] = Wf1[idx];

    // per-row setup (constant over b)
    int e2 = tid >> 1;
    int half = tid & 1;
    int k0 = half * 16;
    int m = e2 & 15, r = e2 >> 4;
    int L0 = 2 * half * 16 + m;
    bool valid = (e2 < 127);
    int t = valid ? (e2 + (e2 >= s)) : 0;
    int pe = s * 127 + (valid ? e2 : 126);
    float sc = 0.f, sh = 0.f;
    if (valid) { sc = statA[pe]; sh = statB[pe]; }

    int col = lane & 15, q4 = (lane >> 4) * 4;
    int qbase = lane & 48;            // quad-base lane (col==0 holder)
    bf16x8 wb2[2], wb3[3];
    wb2[0] = *(const bf16x8*)(W2p + (0 * 64 + lane) * 8);
    wb2[1] = *(const bf16x8*)(W2p + (1 * 64 + lane) * 8);
    wb3[0] = *(const bf16x8*)(W3p + (0 * 64 + lane) * 8);
    wb3[1] = *(const bf16x8*)(W3p + (1 * 64 + lane) * 8);
    wb3[2] = *(const bf16x8*)(W3p + (2 * 64 + lane) * 8);
    float b2c0 = b2[col], b2c1 = b2[16 + col];
    float b3c[3];
    #pragma unroll
    for (int ct = 0; ct < 3; ++ct) {
        int c = ct * 16 + col;
        b3c[ct] = (c < 33) ? b3[c] : 0.f;
    }

    for (int bi = 0; bi < 4; ++bi) {
        int b = o * 4 + bi;
        __syncthreads();                                  // barrier 1

        float nh[16];
        if (valid) {
            const float4* brow = (const float4*)(BT + ((size_t)t * 64 + b) * 32 + k0);
            const float4* ar4  = (const float4*)(AT + ((size_t)s * 64 + b) * 32 + k0);
            #pragma unroll
            for (int q = 0; q < 4; ++q) {
                float4 bv = brow[q];
                float4 av = ar4[q];
                nh[4*q+0] = leakyf((av.x + bv.x) * sc + sh);
                nh[4*q+1] = leakyf((av.y + bv.y) * sc + sh);
                nh[4*q+2] = leakyf((av.z + bv.z) * sc + sh);
                nh[4*q+3] = leakyf((av.w + bv.w) * sc + sh);
            }
        } else {
            #pragma unroll
            for (int q = 0; q < 16; ++q) nh[q] = 0.f;
        }
        bf16x8 v0, v1;
        #pragma unroll
        for (int jj = 0; jj < 8; ++jj) {
            v0[jj] = (short)f2bf(nh[jj]);
            v1[jj] = (short)f2bf(nh[8 + jj]);
        }
        *(bf16x8*)&Abuf[((size_t)r * 64 + L0) * 8]      = v0;
        *(bf16x8*)&Abuf[((size_t)r * 64 + L0 + 16) * 8] = v1;
        __syncthreads();                                  // barrier 2

        // GEMM2
        #pragma unroll
        for (int rt = 0; rt < 2; ++rt) {
            int r2 = w * 2 + rt;
            bf16x8 a = *(const bf16x8*)&Abuf[((size_t)r2 * 64 + lane) * 8];
            f32x4 c0 = {0.f, 0.f, 0.f, 0.f}, c1 = {0.f, 0.f, 0.f, 0.f};
            c0 = __builtin_amdgcn_mfma_f32_16x16x32_bf16(a, wb2[0], c0, 0, 0, 0);
            c1 = __builtin_amdgcn_mfma_f32_16x16x32_bf16(a, wb2[1], c1, 0, 0, 0);
            #pragma unroll
            for (int reg = 0; reg < 4; ++reg) {
                float x = leakyf(c0[reg] + b2c0);
                int c = col;
                Hbuf[((size_t)r2 * 64 + (c >> 3) * 16 + q4 + reg) * 8 + (c & 7)] = f2bf(x);
                float y = leakyf(c1[reg] + b2c1);
                int c2 = 16 + col;
                Hbuf[((size_t)r2 * 64 + (c2 >> 3) * 16 + q4 + reg) * 8 + (c2 & 7)] = f2bf(y);
            }
        }
        __syncthreads();                                  // barrier 3

        // GEMM3
        f32x4 oo[2][3];
        #pragma unroll
        for (int rt = 0; rt < 2; ++rt) {
            int r2 = w * 2 + rt;
            bf16x8 a2 = *(const bf16x8*)&Hbuf[((size_t)r2 * 64 + lane) * 8];
            #pragma unroll
            for (int ct = 0; ct < 3; ++ct) {
                f32x4 cc = {0.f, 0.f, 0.f, 0.f};
                oo[rt][ct] = __builtin_amdgcn_mfma_f32_16x16x32_bf16(a2, wb3[ct], cc, 0, 0, 0);
            }
        }

        // sigmoid in col==0 lanes; broadcast to the quad via shfl (no LDS)
        float ev[2][4];
        #pragma unroll
        for (int rt = 0; rt < 2; ++rt) {
            int row0 = (w * 2 + rt) * 16 + q4;
            float e0 = 0.f, e1 = 0.f, e2v = 0.f, e3 = 0.f;
            if (col == 0) {
                e0  = 1.f / (1.f + __expf(-(oo[rt][0][0] + b3c[0])));
                e1  = 1.f / (1.f + __expf(-(oo[rt][0][1] + b3c[0])));
                e2v = 1.f / (1.f + __expf(-(oo[rt][0][2] + b3c[0])));
                e3  = 1.f / (1.f + __expf(-(oo[rt][0][3] + b3c[0])));
                float* ep = edges_out + (size_t)b * PP + s * 127 + row0;
                ep[0] = e0; ep[1] = e1; ep[2] = e2v;
                if (row0 != 124) ep[3] = e3;
            }
            ev[rt][0] = __shfl(e0,  qbase, 64);
            ev[rt][1] = __shfl(e1,  qbase, 64);
            ev[rt][2] = __shfl(e2v, qbase, 64);
            ev[rt][3] = __shfl(e3,  qbase, 64);
            if (row0 == 124) ev[rt][3] = 0.f;   // pad row 127
        }

        // agg partials: per-lane over own rows, then quad-reduce via shfl_xor
        #pragma unroll
        for (int ct = 0; ct < 3; ++ct) {
            int c = ct * 16 + col;
            if (c >= 1 && c <= 32) {
                float part = 0.f;
                #pragma unroll
                for (int rt = 0; rt < 2; ++rt) {
                    float bb3 = b3c[ct];
                    part += ev[rt][0] * (oo[rt][ct][0] + bb3);
                    part += ev[rt][1] * (oo[rt][ct][1] + bb3);
                    part += ev[rt][2] * (oo[rt][ct][2] + bb3);
                    part += ev[rt][3] * (oo[rt][ct][3] + bb3);
                }
                part += __shfl_xor(part, 16, 64);
                part += __shfl_xor(part, 32, 64);
                if ((lane >> 4) == 0) aggbuf[w][c - 1] = part;
            }
        }
        __syncthreads();                                  // barrier 4

        size_t row = (size_t)b * 128 + s;
        if (tid < 32) {
            float tot = aggbuf[0][tid] + aggbuf[1][tid] + aggbuf[2][tid] + aggbuf[3][tid];
            aggbuf[0][tid] = tot;       // republish total for f-tail (wave 0)
        }
        if (tid < 16) {
            const float* xrow = inputs + row * 32;
            float acc = bf1[tid];
            #pragma unroll
            for (int k = 0; k < 32; ++k) acc += xrow[k] * Wf1s[k * 16 + tid];
            #pragma unroll
            for (int k = 0; k < 32; ++k) acc += aggbuf[0][k] * Wf1s[(32 + k) * 16 + tid];
            f[row * 16 + tid] = acc;
            int bucket = ((blockIdx.x << 2) + bi) & 63;
            atomicAdd(&fpartA[bucket * 16 + tid], acc);
            atomicAdd(&fpartB[bucket * 16 + tid], acc * acc);
        }
    }
}

// ============ Kernel 4: f-stats reduce (redundant per block) + out ============
__global__ __launch_bounds__(256) void out_kernel(
    const float* __restrict__ f,
    const float* __restrict__ fpartA, const float* __restrict__ fpartB,
    const float* __restrict__ gf, const float* __restrict__ bef,
    const float* __restrict__ Wf2, const float* __restrict__ bf2,
    float* __restrict__ outp)
{
    __shared__ float Wf2s[512];
    __shared__ float sc[16], sh[16];
    __shared__ float fs[128];

    int tid = threadIdx.x;
    for (int idx = tid; idx < 512; idx += 256) Wf2s[idx] = Wf2[idx];
    if (tid < 16) {
        float S = 0.f, Q = 0.f;
        #pragma unroll
        for (int g = 0; g < 64; ++g) {
            S += fpartA[g * 16 + tid];
            Q += fpartB[g * 16 + tid];
        }
        float mean = S * (1.f / 8192.f);
        float var  = Q * (1.f / 8192.f) - mean * mean;
        float inv  = rsqrtf(var + EPSF);
        float s2   = inv * gf[tid];
        sc[tid] = s2;
        sh[tid] = bef[tid] - mean * s2;
    }
    int row0 = blockIdx.x * 8;
    if (tid < 128) {
        int r = tid >> 4, j = tid & 15;
        fs[r * 16 + j] = f[(size_t)(row0 + r) * 16 + j];
    }
    __syncthreads();

    int rl = tid >> 5, d = tid & 31;
    float acc = bf2[d];
    #pragma unroll
    for (int j = 0; j < 16; ++j) {
        float v = fs[rl * 16 + j] * sc[j] + sh[j];
        v = leakyf(v);
        acc += v * Wf2s[j * 32 + d];
    }
    outp[(size_t)(row0 + rl) * 32 + d] = acc;
}

extern "C" void kernel_launch(void* const* d_in, const int* in_sizes, int n_in,
                              void* d_out, int out_size, void* d_ws, size_t ws_size,
                              hipStream_t stream) {
    const float* inputs = (const float*)d_in[0];
    const float* W1   = (const float*)d_in[3];
    const float* b1   = (const float*)d_in[4];
    const float* g1   = (const float*)d_in[5];
    const float* be1  = (const float*)d_in[6];
    const float* W2   = (const float*)d_in[7];
    const float* b2   = (const float*)d_in[8];
    const float* W3   = (const float*)d_in[9];
    const float* b3   = (const float*)d_in[10];
    const float* Wf1  = (const float*)d_in[11];
    const float* bf1  = (const float*)d_in[12];
    const float* gf   = (const float*)d_in[13];
    const float* bef  = (const float*)d_in[14];
    const float* Wf2  = (const float*)d_in[15];
    const float* bf2  = (const float*)d_in[16];

    float* ws = (float*)d_ws;
    float* AT     = ws;                              // 262144
    float* BT     = ws + 262144;                     // 262144
    unsigned short* ATh = (unsigned short*)(ws + 524288);  // 262144 ush
    unsigned short* BTh = ATh + 262144;                    // 262144 ush
    float* SQp    = ws + 786432;                     // 2048 (128 n x 4 q x float4)
    float* statA  = ws + 790528;                     // 16256
    float* statB  = ws + 806784;                     // 16256
    float* f      = ws + 823040;                     // 131072
    float* fpartA = ws + 954112;                     // 1024
    float* fpartB = ws + 955136;                     // 1024
    unsigned short* W2p = (unsigned short*)(ws + 956160);  // 1024 ush
    unsigned short* W3p = W2p + 1024;                      // 1536 ush

    float* edges_out = (float*)d_out;                    // B*P
    float* outp      = edges_out + (size_t)BB * PP;      // B*N*D

    proj_kernel<<<512, 256, 0, stream>>>(inputs, W1, b1, W2, W3,
                                         AT, BT, ATh, BTh, SQp,
                                         W2p, W3p, fpartA, fpartB);
    stats2_kernel<<<64, 256, 0, stream>>>(ATh, BTh, SQp, g1, be1, statA, statB);
    edges_kernel<<<2048, 256, 0, stream>>>(AT, BT, statA, statB, W2p, W3p,
                                           b2, b3, inputs, Wf1, bf1,
                                           edges_out, f, fpartA, fpartB);
    out_kernel<<<1024, 256, 0, stream>>>(f, fpartA, fpartB, gf, bef, Wf2, bf2, outp);
}

// Round 10
// 144.991 us; speedup vs baseline: 2.8274x; 1.0021x over previous
//
#include <hip/hip_runtime.h>
#include <hip/hip_bf16.h>
#include <math.h>

#define BB 64
#define NN 128
#define DD 32
#define PP (NN * (NN - 1))   // 16256
#define EPSF 1e-5f

typedef __attribute__((ext_vector_type(8))) short bf16x8;
typedef __attribute__((ext_vector_type(4))) float f32x4;

static __device__ __forceinline__ unsigned short f2bf(float x) {
    unsigned u = __builtin_bit_cast(unsigned, x);
    u += 0x7fff + ((u >> 16) & 1);          // RNE
    return (unsigned short)(u >> 16);
}
static __device__ __forceinline__ unsigned pk2bf(float a, float b) {
    float2 t; t.x = a; t.y = b;
    __hip_bfloat162 h = __float22bfloat162_rn(t);   // v_cvt_pk_bf16_f32
    unsigned u;
    __builtin_memcpy(&u, &h, 4);
    return u;
}
static __device__ __forceinline__ float leakyf(float x) {
    return fmaxf(x, 0.01f * x);
}

// ============ Kernel 1: proj + per-node partial sums + pack + zero ============
// 512 blocks: n = bx>>2, b-quarter q = bx&3 (16 rows). 256 thr.
__global__ __launch_bounds__(256) void proj_kernel(
    const float* __restrict__ inputs, const float* __restrict__ W1,
    const float* __restrict__ b1,
    const float* __restrict__ W2, const float* __restrict__ W3,
    float* __restrict__ AT, float* __restrict__ BT,
    unsigned short* __restrict__ ATh, unsigned short* __restrict__ BTh,
    float* __restrict__ SQp,
    unsigned short* __restrict__ W2p, unsigned short* __restrict__ W3p,
    float* __restrict__ fpartA, float* __restrict__ fpartB)
{
    __shared__ float Xs[16 * 33];
    __shared__ float W1s[2048];
    __shared__ float red[16];

    int tid = threadIdx.x;
    int n = blockIdx.x >> 2, q = blockIdx.x & 3;

    for (int idx = tid; idx < 2048; idx += 256) W1s[idx] = W1[idx];
    for (int idx = tid; idx < 512; idx += 256) {
        int r = idx >> 5, d = idx & 31;
        Xs[r * 33 + d] = inputs[(size_t)(q * 16 + r) * 4096 + n * 32 + d];
    }
    __syncthreads();

    int j = tid & 31, rb = tid >> 5;
    int lane = tid & 63, w = tid >> 6;
    float b1j = b1[j];
    float sa = 0.f, qa = 0.f, sb = 0.f, qb = 0.f;
    #pragma unroll
    for (int i = 0; i < 2; ++i) {
        int r = rb * 2 + i;
        int b = q * 16 + r;
        float a = b1j, c = 0.f;
        #pragma unroll
        for (int k = 0; k < 32; ++k) {
            float x = Xs[r * 33 + k];
            a += x * W1s[k * 32 + j];
            c += x * W1s[(32 + k) * 32 + j];
        }
        size_t off = ((size_t)n * 64 + b) * 32 + j;
        AT[off] = a;  BT[off] = c;
        ATh[off] = f2bf(a);  BTh[off] = f2bf(c);
        sa += a; qa += a * a; sb += c; qb += c * c;
    }
    #pragma unroll
    for (int d = 32; d > 0; d >>= 1) {
        sa += __shfl_down(sa, d, 64);
        qa += __shfl_down(qa, d, 64);
        sb += __shfl_down(sb, d, 64);
        qb += __shfl_down(qb, d, 64);
    }
    if (lane == 0) { red[w*4+0] = sa; red[w*4+1] = qa; red[w*4+2] = sb; red[w*4+3] = qb; }
    __syncthreads();
    if (tid == 0) {
        float4 v;
        v.x = red[0] + red[4] + red[8]  + red[12];
        v.y = red[1] + red[5] + red[9]  + red[13];
        v.z = red[2] + red[6] + red[10] + red[14];
        v.w = red[3] + red[7] + red[11] + red[15];
        ((float4*)SQp)[n * 4 + q] = v;
    }

    if (blockIdx.x == 0 && tid < 64) {      // pack W2/W3 -> bf16 B-frag layout
        int l = tid, nn2 = l & 15, kc = l >> 4;
        #pragma unroll
        for (int ct = 0; ct < 2; ++ct)
            #pragma unroll
            for (int jj = 0; jj < 8; ++jj) {
                int k = kc * 8 + jj;
                W2p[(ct * 64 + l) * 8 + jj] = f2bf(W2[k * 32 + ct * 16 + nn2]);
            }
        #pragma unroll
        for (int ct = 0; ct < 3; ++ct)
            #pragma unroll
            for (int jj = 0; jj < 8; ++jj) {
                int k = kc * 8 + jj;
                int c2 = ct * 16 + nn2;
                W3p[(ct * 64 + l) * 8 + jj] = f2bf(c2 < 33 ? W3[k * 33 + c2] : 0.f);
            }
    }
    if (blockIdx.x == 1) {
        for (int idx = tid; idx < 1024; idx += 256) {
            fpartA[idx] = 0.f;
            fpartB[idx] = 0.f;
        }
    }
}

// ============ Kernel 2: LN stats via bf16 MFMA cross-GEMM ============
// 64 blocks: 16x16 (s,t) tile; 4 waves split K=2048; dual accumulators.
__global__ __launch_bounds__(256) void stats2_kernel(
    const unsigned short* __restrict__ ATh, const unsigned short* __restrict__ BTh,
    const float* __restrict__ SQp,
    const float* __restrict__ g1, const float* __restrict__ be1,
    float* __restrict__ statA, float* __restrict__ statB)
{
    __shared__ __align__(16) float part[4 * 64 * 4];
    int tid = threadIdx.x;
    int lane = tid & 63, w = tid >> 6;
    int s0 = (blockIdx.x >> 3) * 16, t0 = (blockIdx.x & 7) * 16;

    int m = lane & 15, kc = lane >> 4;
    const unsigned short* abase = ATh + (size_t)(s0 + m) * 2048 + kc * 8 + w * 512;
    const unsigned short* bbase = BTh + (size_t)(t0 + m) * 2048 + kc * 8 + w * 512;

    f32x4 acc0 = {0.f, 0.f, 0.f, 0.f}, acc1 = {0.f, 0.f, 0.f, 0.f};
    #pragma unroll
    for (int step = 0; step < 8; ++step) {
        bf16x8 av0 = *(const bf16x8*)(abase + (2 * step) * 32);
        bf16x8 bv0 = *(const bf16x8*)(bbase + (2 * step) * 32);
        acc0 = __builtin_amdgcn_mfma_f32_16x16x32_bf16(av0, bv0, acc0, 0, 0, 0);
        bf16x8 av1 = *(const bf16x8*)(abase + (2 * step + 1) * 32);
        bf16x8 bv1 = *(const bf16x8*)(bbase + (2 * step + 1) * 32);
        acc1 = __builtin_amdgcn_mfma_f32_16x16x32_bf16(av1, bv1, acc1, 0, 0, 0);
    }
    f32x4 acc;
    acc[0] = acc0[0] + acc1[0]; acc[1] = acc0[1] + acc1[1];
    acc[2] = acc0[2] + acc1[2]; acc[3] = acc0[3] + acc1[3];
    *(f32x4*)&part[(w * 64 + lane) * 4] = acc;
    __syncthreads();

    if (w == 0) {
        #pragma unroll
        for (int ww = 1; ww < 4; ++ww) {
            f32x4 o2 = *(const f32x4*)&part[(ww * 64 + lane) * 4];
            acc[0] += o2[0]; acc[1] += o2[1]; acc[2] += o2[2]; acc[3] += o2[3];
        }
        int col = lane & 15, quad = lane >> 4;
        int t = t0 + col;
        float sbt = 0.f, qbt = 0.f;
        #pragma unroll
        for (int o2 = 0; o2 < 4; ++o2) {
            float4 v = ((const float4*)SQp)[t * 4 + o2];
            sbt += v.z; qbt += v.w;
        }
        #pragma unroll
        for (int r = 0; r < 4; ++r) {
            int s = s0 + quad * 4 + r;
            if (s != t) {
                float sas = 0.f, qas = 0.f;
                #pragma unroll
                for (int o2 = 0; o2 < 4; ++o2) {
                    float4 v = ((const float4*)SQp)[s * 4 + o2];
                    sas += v.x; qas += v.y;
                }
                int e = t - (t > s);
                int p = s * 127 + e;
                float S = sas + sbt;
                float Q = qas + qbt + 2.f * acc[r];
                float mean = S * (1.f / 2048.f);
                float var  = Q * (1.f / 2048.f) - mean * mean;
                float inv  = rsqrtf(var + EPSF);
                float sc   = inv * g1[p];
                statA[p] = sc;
                statB[p] = be1[p] - mean * sc;
            }
        }
    }
}

// ============ Kernel 3: MFMA edge MLP + agg + f-rows, b-PAIR per block =======
// 4096 blocks: s = bx&127, o = bx>>7 (0..31) -> batches {2o, 2o+1}. 3 barriers.
__global__ __launch_bounds__(256) void edges_kernel(
    const float* __restrict__ AT, const float* __restrict__ BT,
    const float* __restrict__ statA, const float* __restrict__ statB,
    const unsigned short* __restrict__ W2p, const unsigned short* __restrict__ W3p,
    const float* __restrict__ b2, const float* __restrict__ b3,
    const float* __restrict__ inputs, const float* __restrict__ Wf1,
    const float* __restrict__ bf1,
    float* __restrict__ edges_out,
    float* __restrict__ f, float* __restrict__ fpartA, float* __restrict__ fpartB)
{
    __shared__ __align__(16) unsigned short Abuf[2 * 8 * 64 * 8];  // 16 KB
    __shared__ __align__(16) unsigned short Hbuf[2 * 8 * 64 * 8];  // 16 KB
    __shared__ float Wf1s[1024];                                   // 4 KB
    __shared__ float aggbuf[2][4][32];                             // 1 KB

    int tid = threadIdx.x;
    int s = blockIdx.x & 127;
    int b0 = (blockIdx.x >> 7) * 2;
    int lane = tid & 63, w = tid >> 6;

    for (int idx = tid; idx < 1024; idx += 256) Wf1s[idx] = Wf1[idx];

    // per-row setup (constant over b)
    int e2 = tid >> 1;
    int half = tid & 1;
    int k0 = half * 16;
    int m = e2 & 15, r = e2 >> 4;
    int L0 = 2 * half * 16 + m;
    bool valid = (e2 < 127);
    int t = valid ? (e2 + (e2 >= s)) : 0;
    int pe = s * 127 + (valid ? e2 : 126);
    float sc = 0.f, sh = 0.f;
    if (valid) { sc = statA[pe]; sh = statB[pe]; }

    int col = lane & 15, q4 = (lane >> 4) * 4;
    int qbase = lane & 48;            // quad-base lane (col==0 holder)
    bf16x8 wb2[2], wb3[3];
    wb2[0] = *(const bf16x8*)(W2p + (0 * 64 + lane) * 8);
    wb2[1] = *(const bf16x8*)(W2p + (1 * 64 + lane) * 8);
    wb3[0] = *(const bf16x8*)(W3p + (0 * 64 + lane) * 8);
    wb3[1] = *(const bf16x8*)(W3p + (1 * 64 + lane) * 8);
    wb3[2] = *(const bf16x8*)(W3p + (2 * 64 + lane) * 8);
    float b2c0 = b2[col], b2c1 = b2[16 + col];
    float b3c[3];
    #pragma unroll
    for (int ct = 0; ct < 3; ++ct) {
        int c = ct * 16 + col;
        b3c[ct] = (c < 33) ? b3[c] : 0.f;
    }

    // ---- A-pack: both batches, then ONE barrier ----
    #pragma unroll
    for (int bsel = 0; bsel < 2; ++bsel) {
        int b = b0 + bsel;
        float nh[16];
        if (valid) {
            const float4* brow = (const float4*)(BT + ((size_t)t * 64 + b) * 32 + k0);
            const float4* ar4  = (const float4*)(AT + ((size_t)s * 64 + b) * 32 + k0);
            #pragma unroll
            for (int q = 0; q < 4; ++q) {
                float4 bv = brow[q];
                float4 av = ar4[q];
                nh[4*q+0] = leakyf((av.x + bv.x) * sc + sh);
                nh[4*q+1] = leakyf((av.y + bv.y) * sc + sh);
                nh[4*q+2] = leakyf((av.z + bv.z) * sc + sh);
                nh[4*q+3] = leakyf((av.w + bv.w) * sc + sh);
            }
        } else {
            #pragma unroll
            for (int q = 0; q < 16; ++q) nh[q] = 0.f;
        }
        union { bf16x8 v; unsigned u[4]; } U0, U1;
        #pragma unroll
        for (int q = 0; q < 4; ++q) {
            U0.u[q] = pk2bf(nh[2*q],     nh[2*q+1]);
            U1.u[q] = pk2bf(nh[8+2*q],   nh[8+2*q+1]);
        }
        *(bf16x8*)&Abuf[((size_t)(bsel * 8 + r) * 64 + L0) * 8]      = U0.v;
        *(bf16x8*)&Abuf[((size_t)(bsel * 8 + r) * 64 + L0 + 16) * 8] = U1.v;
    }
    __syncthreads();                                  // barrier 1

    // ---- GEMM2: both batches, then ONE barrier ----
    #pragma unroll
    for (int bsel = 0; bsel < 2; ++bsel) {
        #pragma unroll
        for (int rt = 0; rt < 2; ++rt) {
            int r2 = w * 2 + rt;
            bf16x8 a = *(const bf16x8*)&Abuf[((size_t)(bsel * 8 + r2) * 64 + lane) * 8];
            f32x4 c0 = {0.f, 0.f, 0.f, 0.f}, c1 = {0.f, 0.f, 0.f, 0.f};
            c0 = __builtin_amdgcn_mfma_f32_16x16x32_bf16(a, wb2[0], c0, 0, 0, 0);
            c1 = __builtin_amdgcn_mfma_f32_16x16x32_bf16(a, wb2[1], c1, 0, 0, 0);
            #pragma unroll
            for (int reg = 0; reg < 2; ++reg) {
                // pack pairs (reg even/odd) for cols col and 16+col
                float x0 = leakyf(c0[2*reg]   + b2c0);
                float x1 = leakyf(c0[2*reg+1] + b2c0);
                float y0 = leakyf(c1[2*reg]   + b2c1);
                float y1 = leakyf(c1[2*reg+1] + b2c1);
                int c = col;
                int base = (bsel * 8 + r2) * 64;
                Hbuf[((size_t)base + (c >> 3) * 16 + q4 + 2*reg)     * 8 + (c & 7)] = f2bf(x0);
                Hbuf[((size_t)base + (c >> 3) * 16 + q4 + 2*reg + 1) * 8 + (c & 7)] = f2bf(x1);
                int c2 = 16 + col;
                Hbuf[((size_t)base + (c2 >> 3) * 16 + q4 + 2*reg)     * 8 + (c2 & 7)] = f2bf(y0);
                Hbuf[((size_t)base + (c2 >> 3) * 16 + q4 + 2*reg + 1) * 8 + (c2 & 7)] = f2bf(y1);
            }
        }
    }
    __syncthreads();                                  // barrier 2

    // ---- GEMM3 + epilogue per batch (register-friendly) ----
    #pragma unroll
    for (int bsel = 0; bsel < 2; ++bsel) {
        int b = b0 + bsel;
        f32x4 oo[2][3];
        #pragma unroll
        for (int rt = 0; rt < 2; ++rt) {
            int r2 = w * 2 + rt;
            bf16x8 a2 = *(const bf16x8*)&Hbuf[((size_t)(bsel * 8 + r2) * 64 + lane) * 8];
            #pragma unroll
            for (int ct = 0; ct < 3; ++ct) {
                f32x4 cc = {0.f, 0.f, 0.f, 0.f};
                oo[rt][ct] = __builtin_amdgcn_mfma_f32_16x16x32_bf16(a2, wb3[ct], cc, 0, 0, 0);
            }
        }

        // sigmoid in col==0 lanes; broadcast to quad via shfl
        float ev[2][4];
        #pragma unroll
        for (int rt = 0; rt < 2; ++rt) {
            int row0 = (w * 2 + rt) * 16 + q4;
            float e0 = 0.f, e1 = 0.f, e2v = 0.f, e3 = 0.f;
            if (col == 0) {
                e0  = 1.f / (1.f + __expf(-(oo[rt][0][0] + b3c[0])));
                e1  = 1.f / (1.f + __expf(-(oo[rt][0][1] + b3c[0])));
                e2v = 1.f / (1.f + __expf(-(oo[rt][0][2] + b3c[0])));
                e3  = 1.f / (1.f + __expf(-(oo[rt][0][3] + b3c[0])));
                float* ep = edges_out + (size_t)b * PP + s * 127 + row0;
                ep[0] = e0; ep[1] = e1; ep[2] = e2v;
                if (row0 != 124) ep[3] = e3;
            }
            ev[rt][0] = __shfl(e0,  qbase, 64);
            ev[rt][1] = __shfl(e1,  qbase, 64);
            ev[rt][2] = __shfl(e2v, qbase, 64);
            ev[rt][3] = __shfl(e3,  qbase, 64);
            if (row0 == 124) ev[rt][3] = 0.f;   // pad row 127
        }

        // agg partials: per-lane over own rows, quad-reduce via shfl_xor
        #pragma unroll
        for (int ct = 0; ct < 3; ++ct) {
            int c = ct * 16 + col;
            if (c >= 1 && c <= 32) {
                float part = 0.f;
                #pragma unroll
                for (int rt = 0; rt < 2; ++rt) {
                    float bb3 = b3c[ct];
                    part += ev[rt][0] * (oo[rt][ct][0] + bb3);
                    part += ev[rt][1] * (oo[rt][ct][1] + bb3);
                    part += ev[rt][2] * (oo[rt][ct][2] + bb3);
                    part += ev[rt][3] * (oo[rt][ct][3] + bb3);
                }
                part += __shfl_xor(part, 16, 64);
                part += __shfl_xor(part, 32, 64);
                if ((lane >> 4) == 0) aggbuf[bsel][w][c - 1] = part;
            }
        }
    }
    __syncthreads();                                  // barrier 3

    // ---- f-rows for both batches (sum wave-slices inline) ----
    if (tid < 32) {
        int bsel = tid >> 4, j = tid & 15;
        size_t row = (size_t)(b0 + bsel) * 128 + s;
        const float* xrow = inputs + row * 32;
        float acc = bf1[j];
        #pragma unroll
        for (int k = 0; k < 32; ++k) acc += xrow[k] * Wf1s[k * 16 + j];
        #pragma unroll
        for (int k = 0; k < 32; ++k) {
            float tot = aggbuf[bsel][0][k] + aggbuf[bsel][1][k]
                      + aggbuf[bsel][2][k] + aggbuf[bsel][3][k];
            acc += tot * Wf1s[(32 + k) * 16 + j];
        }
        f[row * 16 + j] = acc;
        int bucket = ((blockIdx.x << 1) + bsel) & 63;
        atomicAdd(&fpartA[bucket * 16 + j], acc);
        atomicAdd(&fpartB[bucket * 16 + j], acc * acc);
    }
}

// ============ Kernel 4: f-stats reduce (redundant per block) + out ============
__global__ __launch_bounds__(256) void out_kernel(
    const float* __restrict__ f,
    const float* __restrict__ fpartA, const float* __restrict__ fpartB,
    const float* __restrict__ gf, const float* __restrict__ bef,
    const float* __restrict__ Wf2, const float* __restrict__ bf2,
    float* __restrict__ outp)
{
    __shared__ float Wf2s[512];
    __shared__ float sc[16], sh[16];
    __shared__ float fs[128];

    int tid = threadIdx.x;
    for (int idx = tid; idx < 512; idx += 256) Wf2s[idx] = Wf2[idx];
    if (tid < 16) {
        float S = 0.f, Q = 0.f;
        #pragma unroll
        for (int g = 0; g < 64; ++g) {
            S += fpartA[g * 16 + tid];
            Q += fpartB[g * 16 + tid];
        }
        float mean = S * (1.f / 8192.f);
        float var  = Q * (1.f / 8192.f) - mean * mean;
        float inv  = rsqrtf(var + EPSF);
        float s2   = inv * gf[tid];
        sc[tid] = s2;
        sh[tid] = bef[tid] - mean * s2;
    }
    int row0 = blockIdx.x * 8;
    if (tid < 128) {
        int r = tid >> 4, j = tid & 15;
        fs[r * 16 + j] = f[(size_t)(row0 + r) * 16 + j];
    }
    __syncthreads();

    int rl = tid >> 5, d = tid & 31;
    float acc = bf2[d];
    #pragma unroll
    for (int j = 0; j < 16; ++j) {
        float v = fs[rl * 16 + j] * sc[j] + sh[j];
        v = leakyf(v);
        acc += v * Wf2s[j * 32 + d];
    }
    outp[(size_t)(row0 + rl) * 32 + d] = acc;
}

extern "C" void kernel_launch(void* const* d_in, const int* in_sizes, int n_in,
                              void* d_out, int out_size, void* d_ws, size_t ws_size,
                              hipStream_t stream) {
    const float* inputs = (const float*)d_in[0];
    const float* W1   = (const float*)d_in[3];
    const float* b1   = (const float*)d_in[4];
    const float* g1   = (const float*)d_in[5];
    const float* be1  = (const float*)d_in[6];
    const float* W2   = (const float*)d_in[7];
    const float* b2   = (const float*)d_in[8];
    const float* W3   = (const float*)d_in[9];
    const float* b3   = (const float*)d_in[10];
    const float* Wf1  = (const float*)d_in[11];
    const float* bf1  = (const float*)d_in[12];
    const float* gf   = (const float*)d_in[13];
    const float* bef  = (const float*)d_in[14];
    const float* Wf2  = (const float*)d_in[15];
    const float* bf2  = (const float*)d_in[16];

    float* ws = (float*)d_ws;
    float* AT     = ws;                              // 262144
    float* BT     = ws + 262144;                     // 262144
    unsigned short* ATh = (unsigned short*)(ws + 524288);  // 262144 ush
    unsigned short* BTh = ATh + 262144;                    // 262144 ush
    float* SQp    = ws + 786432;                     // 2048 (128 n x 4 q x float4)
    float* statA  = ws + 790528;                     // 16256
    float* statB  = ws + 806784;                     // 16256
    float* f      = ws + 823040;                     // 131072
    float* fpartA = ws + 954112;                     // 1024
    float* fpartB = ws + 955136;                     // 1024
    unsigned short* W2p = (unsigned short*)(ws + 956160);  // 1024 ush
    unsigned short* W3p = W2p + 1024;                      // 1536 ush

    float* edges_out = (float*)d_out;                    // B*P
    float* outp      = edges_out + (size_t)BB * PP;      // B*N*D

    proj_kernel<<<512, 256, 0, stream>>>(inputs, W1, b1, W2, W3,
                                         AT, BT, ATh, BTh, SQp,
                                         W2p, W3p, fpartA, fpartB);
    stats2_kernel<<<64, 256, 0, stream>>>(ATh, BTh, SQp, g1, be1, statA, statB);
    edges_kernel<<<4096, 256, 0, stream>>>(AT, BT, statA, statB, W2p, W3p,
                                           b2, b3, inputs, Wf1, bf1,
                                           edges_out, f, fpartA, fpartB);
    out_kernel<<<1024, 256, 0, stream>>>(f, fpartA, fpartB, gf, bef, Wf2, bf2, outp);
}

// Round 11
// 142.660 us; speedup vs baseline: 2.8736x; 1.0163x over previous
//
#include <hip/hip_runtime.h>
#include <hip/hip_bf16.h>
#include <math.h>

#define BB 64
#define NN 128
#define DD 32
#define PP (NN * (NN - 1))   // 16256
#define EPSF 1e-5f

typedef __attribute__((ext_vector_type(8))) short bf16x8;
typedef __attribute__((ext_vector_type(4))) float f32x4;

static __device__ __forceinline__ unsigned short f2bf(float x) {
    unsigned u = __builtin_bit_cast(unsigned, x);
    u += 0x7fff + ((u >> 16) & 1);          // RNE
    return (unsigned short)(u >> 16);
}
static __device__ __forceinline__ unsigned pk2bf(float a, float b) {
    float2 t; t.x = a; t.y = b;
    __hip_bfloat162 h = __float22bfloat162_rn(t);   // v_cvt_pk_bf16_f32
    unsigned u;
    __builtin_memcpy(&u, &h, 4);
    return u;
}
static __device__ __forceinline__ float leakyf(float x) {
    return fmaxf(x, 0.01f * x);
}

// ============ Kernel 1: proj + per-node partial sums + pack + zero ============
// 512 blocks: n = bx>>2, b-quarter q = bx&3 (16 rows). 256 thr.
__global__ __launch_bounds__(256) void proj_kernel(
    const float* __restrict__ inputs, const float* __restrict__ W1,
    const float* __restrict__ b1,
    const float* __restrict__ W2, const float* __restrict__ W3,
    float* __restrict__ AT, float* __restrict__ BT,
    unsigned short* __restrict__ ATh, unsigned short* __restrict__ BTh,
    float* __restrict__ SQp,
    unsigned short* __restrict__ W2p, unsigned short* __restrict__ W3p,
    float* __restrict__ fpartA, float* __restrict__ fpartB)
{
    __shared__ float Xs[16 * 33];
    __shared__ float W1s[2048];
    __shared__ float red[16];

    int tid = threadIdx.x;
    int n = blockIdx.x >> 2, q = blockIdx.x & 3;

    for (int idx = tid; idx < 2048; idx += 256) W1s[idx] = W1[idx];
    for (int idx = tid; idx < 512; idx += 256) {
        int r = idx >> 5, d = idx & 31;
        Xs[r * 33 + d] = inputs[(size_t)(q * 16 + r) * 4096 + n * 32 + d];
    }
    __syncthreads();

    int j = tid & 31, rb = tid >> 5;
    int lane = tid & 63, w = tid >> 6;
    float b1j = b1[j];
    float sa = 0.f, qa = 0.f, sb = 0.f, qb = 0.f;
    #pragma unroll
    for (int i = 0; i < 2; ++i) {
        int r = rb * 2 + i;
        int b = q * 16 + r;
        float a = b1j, c = 0.f;
        #pragma unroll
        for (int k = 0; k < 32; ++k) {
            float x = Xs[r * 33 + k];
            a += x * W1s[k * 32 + j];
            c += x * W1s[(32 + k) * 32 + j];
        }
        size_t off = ((size_t)n * 64 + b) * 32 + j;
        AT[off] = a;  BT[off] = c;
        ATh[off] = f2bf(a);  BTh[off] = f2bf(c);
        sa += a; qa += a * a; sb += c; qb += c * c;
    }
    #pragma unroll
    for (int d = 32; d > 0; d >>= 1) {
        sa += __shfl_down(sa, d, 64);
        qa += __shfl_down(qa, d, 64);
        sb += __shfl_down(sb, d, 64);
        qb += __shfl_down(qb, d, 64);
    }
    if (lane == 0) { red[w*4+0] = sa; red[w*4+1] = qa; red[w*4+2] = sb; red[w*4+3] = qb; }
    __syncthreads();
    if (tid == 0) {
        float4 v;
        v.x = red[0] + red[4] + red[8]  + red[12];
        v.y = red[1] + red[5] + red[9]  + red[13];
        v.z = red[2] + red[6] + red[10] + red[14];
        v.w = red[3] + red[7] + red[11] + red[15];
        ((float4*)SQp)[n * 4 + q] = v;
    }

    if (blockIdx.x == 0 && tid < 64) {      // pack W2/W3 -> bf16 B-frag layout
        int l = tid, nn2 = l & 15, kc = l >> 4;
        #pragma unroll
        for (int ct = 0; ct < 2; ++ct)
            #pragma unroll
            for (int jj = 0; jj < 8; ++jj) {
                int k = kc * 8 + jj;
                W2p[(ct * 64 + l) * 8 + jj] = f2bf(W2[k * 32 + ct * 16 + nn2]);
            }
        #pragma unroll
        for (int ct = 0; ct < 3; ++ct)
            #pragma unroll
            for (int jj = 0; jj < 8; ++jj) {
                int k = kc * 8 + jj;
                int c2 = ct * 16 + nn2;
                W3p[(ct * 64 + l) * 8 + jj] = f2bf(c2 < 33 ? W3[k * 33 + c2] : 0.f);
            }
    }
    if (blockIdx.x == 1) {
        for (int idx = tid; idx < 1024; idx += 256) {
            fpartA[idx] = 0.f;
            fpartB[idx] = 0.f;
        }
    }
}

// ============ Kernel 2: LN stats via bf16 MFMA cross-GEMM ============
// 64 blocks: 16x16 (s,t) tile; 4 waves split K=2048; dual accumulators.
__global__ __launch_bounds__(256) void stats2_kernel(
    const unsigned short* __restrict__ ATh, const unsigned short* __restrict__ BTh,
    const float* __restrict__ SQp,
    const float* __restrict__ g1, const float* __restrict__ be1,
    float* __restrict__ statA, float* __restrict__ statB)
{
    __shared__ __align__(16) float part[4 * 64 * 4];
    int tid = threadIdx.x;
    int lane = tid & 63, w = tid >> 6;
    int s0 = (blockIdx.x >> 3) * 16, t0 = (blockIdx.x & 7) * 16;

    int m = lane & 15, kc = lane >> 4;
    const unsigned short* abase = ATh + (size_t)(s0 + m) * 2048 + kc * 8 + w * 512;
    const unsigned short* bbase = BTh + (size_t)(t0 + m) * 2048 + kc * 8 + w * 512;

    f32x4 acc0 = {0.f, 0.f, 0.f, 0.f}, acc1 = {0.f, 0.f, 0.f, 0.f};
    #pragma unroll
    for (int step = 0; step < 8; ++step) {
        bf16x8 av0 = *(const bf16x8*)(abase + (2 * step) * 32);
        bf16x8 bv0 = *(const bf16x8*)(bbase + (2 * step) * 32);
        acc0 = __builtin_amdgcn_mfma_f32_16x16x32_bf16(av0, bv0, acc0, 0, 0, 0);
        bf16x8 av1 = *(const bf16x8*)(abase + (2 * step + 1) * 32);
        bf16x8 bv1 = *(const bf16x8*)(bbase + (2 * step + 1) * 32);
        acc1 = __builtin_amdgcn_mfma_f32_16x16x32_bf16(av1, bv1, acc1, 0, 0, 0);
    }
    f32x4 acc;
    acc[0] = acc0[0] + acc1[0]; acc[1] = acc0[1] + acc1[1];
    acc[2] = acc0[2] + acc1[2]; acc[3] = acc0[3] + acc1[3];
    *(f32x4*)&part[(w * 64 + lane) * 4] = acc;
    __syncthreads();

    if (w == 0) {
        #pragma unroll
        for (int ww = 1; ww < 4; ++ww) {
            f32x4 o2 = *(const f32x4*)&part[(ww * 64 + lane) * 4];
            acc[0] += o2[0]; acc[1] += o2[1]; acc[2] += o2[2]; acc[3] += o2[3];
        }
        int col = lane & 15, quad = lane >> 4;
        int t = t0 + col;
        float sbt = 0.f, qbt = 0.f;
        #pragma unroll
        for (int o2 = 0; o2 < 4; ++o2) {
            float4 v = ((const float4*)SQp)[t * 4 + o2];
            sbt += v.z; qbt += v.w;
        }
        #pragma unroll
        for (int r = 0; r < 4; ++r) {
            int s = s0 + quad * 4 + r;
            if (s != t) {
                float sas = 0.f, qas = 0.f;
                #pragma unroll
                for (int o2 = 0; o2 < 4; ++o2) {
                    float4 v = ((const float4*)SQp)[s * 4 + o2];
                    sas += v.x; qas += v.y;
                }
                int e = t - (t > s);
                int p = s * 127 + e;
                float S = sas + sbt;
                float Q = qas + qbt + 2.f * acc[r];
                float mean = S * (1.f / 2048.f);
                float var  = Q * (1.f / 2048.f) - mean * mean;
                float inv  = rsqrtf(var + EPSF);
                float sc   = inv * g1[p];
                statA[p] = sc;
                statB[p] = be1[p] - mean * sc;
            }
        }
    }
}

// ============ Kernel 3: edge MLP, wave-private pipeline, ONE barrier =========
// 8192 blocks: s = bx&127, b = bx>>7. 4 waves x 2 row-tiles of 16 edges.
// A-fragment built DIRECTLY from global loads (lane slice = 8 contiguous
// floats of one edge row) -- no LDS staging, no barrier until the f-tail.
__global__ __launch_bounds__(256) void edges_kernel(
    const float* __restrict__ AT, const float* __restrict__ BT,
    const float* __restrict__ statA, const float* __restrict__ statB,
    const unsigned short* __restrict__ W2p, const unsigned short* __restrict__ W3p,
    const float* __restrict__ b2, const float* __restrict__ b3,
    const float* __restrict__ inputs, const float* __restrict__ Wf1,
    const float* __restrict__ bf1,
    float* __restrict__ edges_out,
    float* __restrict__ f, float* __restrict__ fpartA, float* __restrict__ fpartB)
{
    __shared__ __align__(16) unsigned short Hs[4][512];   // per-wave 16x32 swizzled
    __shared__ float Wf1s[1024];
    __shared__ float aggbuf[4][32];

    int tid = threadIdx.x;
    int s = blockIdx.x & 127;
    int b = blockIdx.x >> 7;
    int lane = tid & 63, w = tid >> 6;
    int m = lane & 15;          // A-frag row within tile / C-frag col
    int kb = lane >> 4;         // k-block (8 wide)
    int col = m;
    int q4 = kb * 4;            // C-frag row group
    int qbase = lane & 48;

    for (int idx = tid; idx < 1024; idx += 256) Wf1s[idx] = Wf1[idx];

    // B fragments + biases (block-invariant)
    bf16x8 wb2[2], wb3[3];
    wb2[0] = *(const bf16x8*)(W2p + (0 * 64 + lane) * 8);
    wb2[1] = *(const bf16x8*)(W2p + (1 * 64 + lane) * 8);
    wb3[0] = *(const bf16x8*)(W3p + (0 * 64 + lane) * 8);
    wb3[1] = *(const bf16x8*)(W3p + (1 * 64 + lane) * 8);
    wb3[2] = *(const bf16x8*)(W3p + (2 * 64 + lane) * 8);
    float b2c0 = b2[col], b2c1 = b2[16 + col];
    float b3c[3];
    #pragma unroll
    for (int ct = 0; ct < 3; ++ct) {
        int c = ct * 16 + col;
        b3c[ct] = (c < 33) ? b3[c] : 0.f;
    }

    // lane's AT slice (same for both tiles)
    const float4* asl = (const float4*)(AT + ((size_t)s * 64 + b) * 32 + kb * 8);
    float4 a0 = asl[0], a1 = asl[1];

    float aggpart[3] = {0.f, 0.f, 0.f};

    #pragma unroll
    for (int rt = 0; rt < 2; ++rt) {
        int tile = w * 2 + rt;
        int e = tile * 16 + m;
        bool valid = (e < 127);
        int ee = valid ? e : 0;
        int t = ee + (ee >= s);
        int p = s * 127 + ee;
        float sc = statA[p], sh = statB[p];

        const float4* bsl = (const float4*)(BT + ((size_t)t * 64 + b) * 32 + kb * 8);
        float4 bv0 = bsl[0], bv1 = bsl[1];

        float nh[8];
        nh[0] = leakyf((a0.x + bv0.x) * sc + sh);
        nh[1] = leakyf((a0.y + bv0.y) * sc + sh);
        nh[2] = leakyf((a0.z + bv0.z) * sc + sh);
        nh[3] = leakyf((a0.w + bv0.w) * sc + sh);
        nh[4] = leakyf((a1.x + bv1.x) * sc + sh);
        nh[5] = leakyf((a1.y + bv1.y) * sc + sh);
        nh[6] = leakyf((a1.z + bv1.z) * sc + sh);
        nh[7] = leakyf((a1.w + bv1.w) * sc + sh);
        if (!valid) {
            #pragma unroll
            for (int q = 0; q < 8; ++q) nh[q] = 0.f;
        }
        union { bf16x8 v; unsigned u[4]; } AF;
        #pragma unroll
        for (int q = 0; q < 4; ++q) AF.u[q] = pk2bf(nh[2*q], nh[2*q+1]);

        // GEMM2: h2 tile (C layout)
        f32x4 c0 = {0.f, 0.f, 0.f, 0.f}, c1 = {0.f, 0.f, 0.f, 0.f};
        c0 = __builtin_amdgcn_mfma_f32_16x16x32_bf16(AF.v, wb2[0], c0, 0, 0, 0);
        c1 = __builtin_amdgcn_mfma_f32_16x16x32_bf16(AF.v, wb2[1], c1, 0, 0, 0);

        // C -> A transpose via wave-private swizzled scratch (no barrier)
        #pragma unroll
        for (int reg = 0; reg < 4; ++reg) {
            int row = q4 + reg;
            float x = leakyf(c0[reg] + b2c0);
            float y = leakyf(c1[reg] + b2c1);
            int cA = col;            // < 16
            int cB = col + 16;
            Hs[w][row * 32 + (((cA >> 3) ^ (row >> 2)) & 3) * 8 + (cA & 7)] = f2bf(x);
            Hs[w][row * 32 + (((cB >> 3) ^ (row >> 2)) & 3) * 8 + (cB & 7)] = f2bf(y);
        }
        // wave-synchronous read-back (compiler emits lgkmcnt wait)
        bf16x8 a2 = *(const bf16x8*)&Hs[w][m * 32 + ((kb ^ (m >> 2)) & 3) * 8];

        // GEMM3
        f32x4 oo[3];
        #pragma unroll
        for (int ct = 0; ct < 3; ++ct) {
            f32x4 cc = {0.f, 0.f, 0.f, 0.f};
            oo[ct] = __builtin_amdgcn_mfma_f32_16x16x32_bf16(a2, wb3[ct], cc, 0, 0, 0);
        }

        // sigmoid on col 0 (lanes with col==0 hold rows q4+reg), then quad shfl
        float v0 = 0.f, v1 = 0.f, v2 = 0.f, v3 = 0.f;
        int grow0 = tile * 16 + q4;
        if (col == 0) {
            v0 = 1.f / (1.f + __expf(-(oo[0][0] + b3c[0])));
            v1 = 1.f / (1.f + __expf(-(oo[0][1] + b3c[0])));
            v2 = 1.f / (1.f + __expf(-(oo[0][2] + b3c[0])));
            v3 = (grow0 == 124) ? 0.f
               : 1.f / (1.f + __expf(-(oo[0][3] + b3c[0])));
            float* ep = edges_out + (size_t)b * PP + s * 127 + grow0;
            ep[0] = v0; ep[1] = v1; ep[2] = v2;
            if (grow0 != 124) ep[3] = v3;
        }
        float ev0 = __shfl(v0, qbase, 64);
        float ev1 = __shfl(v1, qbase, 64);
        float ev2 = __shfl(v2, qbase, 64);
        float ev3 = __shfl(v3, qbase, 64);

        // agg partials (cols 1..32 of the 48-wide output)
        #pragma unroll
        for (int ct = 0; ct < 3; ++ct) {
            float bb3 = b3c[ct];
            float pt = ev0 * (oo[ct][0] + bb3) + ev1 * (oo[ct][1] + bb3)
                     + ev2 * (oo[ct][2] + bb3) + ev3 * (oo[ct][3] + bb3);
            aggpart[ct] += pt;
        }
    }

    // quad-reduce agg partials (sum over kb groups = rows), store wave slice
    #pragma unroll
    for (int ct = 0; ct < 3; ++ct) {
        float pt = aggpart[ct];
        pt += __shfl_xor(pt, 16, 64);
        pt += __shfl_xor(pt, 32, 64);
        int c = ct * 16 + col;
        if (kb == 0 && c >= 1 && c <= 32) aggbuf[w][c - 1] = pt;
    }
    __syncthreads();                                   // the ONLY barrier

    // f-row tail
    if (tid < 16) {
        size_t row = (size_t)b * 128 + s;
        const float* xrow = inputs + row * 32;
        float acc = bf1[tid];
        #pragma unroll
        for (int k = 0; k < 32; ++k) acc += xrow[k] * Wf1s[k * 16 + tid];
        #pragma unroll
        for (int k = 0; k < 32; ++k) {
            float tot = aggbuf[0][k] + aggbuf[1][k] + aggbuf[2][k] + aggbuf[3][k];
            acc += tot * Wf1s[(32 + k) * 16 + tid];
        }
        f[row * 16 + tid] = acc;
        int bucket = blockIdx.x & 63;
        atomicAdd(&fpartA[bucket * 16 + tid], acc);
        atomicAdd(&fpartB[bucket * 16 + tid], acc * acc);
    }
}

// ============ Kernel 4: f-stats reduce (redundant per block) + out ============
__global__ __launch_bounds__(256) void out_kernel(
    const float* __restrict__ f,
    const float* __restrict__ fpartA, const float* __restrict__ fpartB,
    const float* __restrict__ gf, const float* __restrict__ bef,
    const float* __restrict__ Wf2, const float* __restrict__ bf2,
    float* __restrict__ outp)
{
    __shared__ float Wf2s[512];
    __shared__ float sc[16], sh[16];
    __shared__ float fs[128];

    int tid = threadIdx.x;
    for (int idx = tid; idx < 512; idx += 256) Wf2s[idx] = Wf2[idx];
    if (tid < 16) {
        float S = 0.f, Q = 0.f;
        #pragma unroll
        for (int g = 0; g < 64; ++g) {
            S += fpartA[g * 16 + tid];
            Q += fpartB[g * 16 + tid];
        }
        float mean = S * (1.f / 8192.f);
        float var  = Q * (1.f / 8192.f) - mean * mean;
        float inv  = rsqrtf(var + EPSF);
        float s2   = inv * gf[tid];
        sc[tid] = s2;
        sh[tid] = bef[tid] - mean * s2;
    }
    int row0 = blockIdx.x * 8;
    if (tid < 128) {
        int r = tid >> 4, j = tid & 15;
        fs[r * 16 + j] = f[(size_t)(row0 + r) * 16 + j];
    }
    __syncthreads();

    int rl = tid >> 5, d = tid & 31;
    float acc = bf2[d];
    #pragma unroll
    for (int j = 0; j < 16; ++j) {
        float v = fs[rl * 16 + j] * sc[j] + sh[j];
        v = leakyf(v);
        acc += v * Wf2s[j * 32 + d];
    }
    outp[(size_t)(row0 + rl) * 32 + d] = acc;
}

extern "C" void kernel_launch(void* const* d_in, const int* in_sizes, int n_in,
                              void* d_out, int out_size, void* d_ws, size_t ws_size,
                              hipStream_t stream) {
    const float* inputs = (const float*)d_in[0];
    const float* W1   = (const float*)d_in[3];
    const float* b1   = (const float*)d_in[4];
    const float* g1   = (const float*)d_in[5];
    const float* be1  = (const float*)d_in[6];
    const float* W2   = (const float*)d_in[7];
    const float* b2   = (const float*)d_in[8];
    const float* W3   = (const float*)d_in[9];
    const float* b3   = (const float*)d_in[10];
    const float* Wf1  = (const float*)d_in[11];
    const float* bf1  = (const float*)d_in[12];
    const float* gf   = (const float*)d_in[13];
    const float* bef  = (const float*)d_in[14];
    const float* Wf2  = (const float*)d_in[15];
    const float* bf2  = (const float*)d_in[16];

    float* ws = (float*)d_ws;
    float* AT     = ws;                              // 262144
    float* BT     = ws + 262144;                     // 262144
    unsigned short* ATh = (unsigned short*)(ws + 524288);  // 262144 ush
    unsigned short* BTh = ATh + 262144;                    // 262144 ush
    float* SQp    = ws + 786432;                     // 2048 (128 n x 4 q x float4)
    float* statA  = ws + 790528;                     // 16256
    float* statB  = ws + 806784;                     // 16256
    float* f      = ws + 823040;                     // 131072
    float* fpartA = ws + 954112;                     // 1024
    float* fpartB = ws + 955136;                     // 1024
    unsigned short* W2p = (unsigned short*)(ws + 956160);  // 1024 ush
    unsigned short* W3p = W2p + 1024;                      // 1536 ush

    float* edges_out = (float*)d_out;                    // B*P
    float* outp      = edges_out + (size_t)BB * PP;      // B*N*D

    proj_kernel<<<512, 256, 0, stream>>>(inputs, W1, b1, W2, W3,
                                         AT, BT, ATh, BTh, SQp,
                                         W2p, W3p, fpartA, fpartB);
    stats2_kernel<<<64, 256, 0, stream>>>(ATh, BTh, SQp, g1, be1, statA, statB);
    edges_kernel<<<8192, 256, 0, stream>>>(AT, BT, statA, statB, W2p, W3p,
                                           b2, b3, inputs, Wf1, bf1,
                                           edges_out, f, fpartA, fpartB);
    out_kernel<<<1024, 256, 0, stream>>>(f, fpartA, fpartB, gf, bef, Wf2, bf2, outp);
}